// Round 1
// baseline (528.715 us; speedup 1.0000x reference)
//
#include <hip/hip_runtime.h>

#define N_NODES 100000
#define N_EDGES 1600000
#define DIM 64

// float atomic max via integer ordering trick:
// - non-negative floats compare correctly as signed ints
// - negative floats compare inverted as unsigned ints (more negative = larger uint)
__device__ __forceinline__ void atomicMaxF32(float* addr, float val) {
    if (val >= 0.0f) {
        atomicMax((int*)addr, __float_as_int(val));
    } else {
        atomicMin((unsigned int*)addr, __float_as_uint(val));
    }
}

__device__ __forceinline__ float leaky01(float x) {
    return x >= 0.0f ? x : 0.01f * x;
}

// Per-node precompute: a_src[n] = W[0:64] . h[n], a_dst[n] = W[64:128] . h[n] + b
// 16 lanes per node, float4 per lane, shfl_xor reduce within the 16-lane group.
// Also initializes e_max = -inf, e_sum = 0.
__global__ void node_pre(const float* __restrict__ h,
                         const float* __restrict__ W,
                         const float* __restrict__ b,
                         float* __restrict__ a_src,
                         float* __restrict__ a_dst,
                         float* __restrict__ e_max,
                         float* __restrict__ e_sum) {
    int tid  = blockIdx.x * blockDim.x + threadIdx.x;
    int lane = threadIdx.x & 63;
    int grp  = lane >> 4;     // 4 nodes per wave
    int j    = lane & 15;     // float4 slot within the 64-dim row
    int wave = tid >> 6;
    int node = wave * 4 + grp;
    if (node >= N_NODES) return;  // uniform per 16-lane group

    float4 hv = *reinterpret_cast<const float4*>(h + (size_t)node * DIM + j * 4);
    float4 ws = *reinterpret_cast<const float4*>(W + j * 4);
    float4 wd = *reinterpret_cast<const float4*>(W + 64 + j * 4);
    float s = hv.x * ws.x + hv.y * ws.y + hv.z * ws.z + hv.w * ws.w;
    float d = hv.x * wd.x + hv.y * wd.y + hv.z * wd.z + hv.w * wd.w;
    #pragma unroll
    for (int m = 1; m < 16; m <<= 1) {
        s += __shfl_xor(s, m);
        d += __shfl_xor(d, m);
    }
    if (j == 0) {
        a_src[node] = s;
        a_dst[node] = d + b[0];
        e_max[node] = __int_as_float(0xFF800000);  // -inf
        e_sum[node] = 0.0f;
    }
}

// Pass 1 over edges: segment max of e over dst.
__global__ void edge_max(const int* __restrict__ src,
                         const int* __restrict__ dst,
                         const float* __restrict__ a_src,
                         const float* __restrict__ a_dst,
                         float* __restrict__ e_max) {
    int i = blockIdx.x * blockDim.x + threadIdx.x;
    if (i >= N_EDGES) return;
    int s = src[i], d = dst[i];
    float e = leaky01(a_src[s] + a_dst[d]);
    atomicMaxF32(&e_max[d], e);
}

// Pass 2 over edges: segment sum of exp(e - e_max[dst]).
__global__ void edge_sum(const int* __restrict__ src,
                         const int* __restrict__ dst,
                         const float* __restrict__ a_src,
                         const float* __restrict__ a_dst,
                         const float* __restrict__ e_max,
                         float* __restrict__ e_sum) {
    int i = blockIdx.x * blockDim.x + threadIdx.x;
    if (i >= N_EDGES) return;
    int s = src[i], d = dst[i];
    float e = leaky01(a_src[s] + a_dst[d]);
    atomicAdd(&e_sum[d], expf(e - e_max[d]));
}

// Pass 3: one wave per edge, lane = feature dim.
// out[dst] += alpha * h[src]  via 64 coalesced f32 atomics per edge.
__global__ void edge_aggregate(const int* __restrict__ src,
                               const int* __restrict__ dst,
                               const float* __restrict__ a_src,
                               const float* __restrict__ a_dst,
                               const float* __restrict__ e_max,
                               const float* __restrict__ e_sum,
                               const float* __restrict__ h,
                               float* __restrict__ out) {
    long tid  = (long)blockIdx.x * blockDim.x + threadIdx.x;
    long edge = tid >> 6;
    int  lane = threadIdx.x & 63;
    if (edge >= N_EDGES) return;
    int s = src[edge], d = dst[edge];
    float e     = leaky01(a_src[s] + a_dst[d]);
    float alpha = expf(e - e_max[d]) / e_sum[d];
    atomicAdd(&out[(size_t)d * DIM + lane], alpha * h[(size_t)s * DIM + lane]);
}

extern "C" void kernel_launch(void* const* d_in, const int* in_sizes, int n_in,
                              void* d_out, int out_size, void* d_ws, size_t ws_size,
                              hipStream_t stream) {
    const float* h   = (const float*)d_in[0];
    const int*   src = (const int*)d_in[1];
    const int*   dst = (const int*)d_in[2];
    const float* W   = (const float*)d_in[3];
    const float* b   = (const float*)d_in[4];
    float*       out = (float*)d_out;

    // workspace partition: 4 * N_NODES floats = 1.6 MB
    float* a_src = (float*)d_ws;
    float* a_dst = a_src + N_NODES;
    float* e_max = a_dst + N_NODES;
    float* e_sum = e_max + N_NODES;

    // out must start at zero every call (harness poisons once, never restores)
    hipMemsetAsync(d_out, 0, (size_t)out_size * sizeof(float), stream);

    // node precompute: 4 nodes/wave, 4 waves/block -> 16 nodes/block
    int node_blocks = (N_NODES + 15) / 16;  // 6250
    node_pre<<<node_blocks, 256, 0, stream>>>(h, W, b, a_src, a_dst, e_max, e_sum);

    int edge_blocks = (N_EDGES + 255) / 256;  // 6250
    edge_max<<<edge_blocks, 256, 0, stream>>>(src, dst, a_src, a_dst, e_max);
    edge_sum<<<edge_blocks, 256, 0, stream>>>(src, dst, a_src, a_dst, e_max, e_sum);

    // one wave per edge -> N_EDGES waves, 4 waves/block
    int agg_blocks = (N_EDGES + 3) / 4;  // 400000
    edge_aggregate<<<agg_blocks, 256, 0, stream>>>(src, dst, a_src, a_dst,
                                                   e_max, e_sum, h, out);
}

// Round 2
// 321.293 us; speedup vs baseline: 1.6456x; 1.6456x over previous
//
#include <hip/hip_runtime.h>

#define N_NODES 100000
#define N_EDGES 1600000
#define DIM 64
#define NEG_INF __int_as_float(0xFF800000)

__device__ __forceinline__ float leaky01(float x) {
    return x >= 0.0f ? x : 0.01f * x;
}

// Per-node precompute: a_src[n] = W[0:64].h[n], a_dst[n] = W[64:128].h[n] + b
__global__ void node_pre(const float* __restrict__ h,
                         const float* __restrict__ W,
                         const float* __restrict__ b,
                         float* __restrict__ a_src,
                         float* __restrict__ a_dst) {
    int tid  = blockIdx.x * blockDim.x + threadIdx.x;
    int lane = threadIdx.x & 63;
    int grp  = lane >> 4;     // 4 nodes per wave
    int j    = lane & 15;     // float4 slot within the 64-dim row
    int wave = tid >> 6;
    int node = wave * 4 + grp;
    if (node >= N_NODES) return;  // uniform per 16-lane group

    float4 hv = *reinterpret_cast<const float4*>(h + (size_t)node * DIM + j * 4);
    float4 ws = *reinterpret_cast<const float4*>(W + j * 4);
    float4 wd = *reinterpret_cast<const float4*>(W + DIM + j * 4);
    float s = hv.x * ws.x + hv.y * ws.y + hv.z * ws.z + hv.w * ws.w;
    float d = hv.x * wd.x + hv.y * wd.y + hv.z * wd.z + hv.w * wd.w;
    #pragma unroll
    for (int m = 1; m < 16; m <<= 1) {
        s += __shfl_xor(s, m);
        d += __shfl_xor(d, m);
    }
    if (j == 0) {
        a_src[node] = s;
        a_dst[node] = d + b[0];
    }
}

// Degree histogram over dst. deg must be pre-zeroed.
__global__ void hist(const int* __restrict__ dst, int* __restrict__ deg) {
    int i = blockIdx.x * blockDim.x + threadIdx.x;
    if (i >= N_EDGES) return;
    atomicAdd(&deg[dst[i]], 1);
}

// Two-level exclusive scan over deg[N_NODES] -> offsets.
__global__ void scan1(const int* __restrict__ deg,
                      int* __restrict__ offsets,
                      int* __restrict__ blockSums) {
    __shared__ int tmp[256];
    int gid = blockIdx.x * 256 + threadIdx.x;
    int v = (gid < N_NODES) ? deg[gid] : 0;
    tmp[threadIdx.x] = v;
    __syncthreads();
    for (int off = 1; off < 256; off <<= 1) {
        int t = 0;
        if ((int)threadIdx.x >= off) t = tmp[threadIdx.x - off];
        __syncthreads();
        if ((int)threadIdx.x >= off) tmp[threadIdx.x] += t;
        __syncthreads();
    }
    if (gid < N_NODES) offsets[gid] = tmp[threadIdx.x] - v;  // exclusive
    if (threadIdx.x == 255) blockSums[blockIdx.x] = tmp[255];
}

__global__ void scan2(int* __restrict__ blockSums, int nblocks) {
    __shared__ int tmp[512];
    int t = threadIdx.x;
    int v = (t < nblocks) ? blockSums[t] : 0;
    tmp[t] = v;
    __syncthreads();
    for (int off = 1; off < 512; off <<= 1) {
        int x = 0;
        if (t >= off) x = tmp[t - off];
        __syncthreads();
        if (t >= off) tmp[t] += x;
        __syncthreads();
    }
    if (t < nblocks) blockSums[t] = tmp[t] - v;  // exclusive
}

__global__ void scan3(int* __restrict__ offsets,
                      const int* __restrict__ blockSums,
                      int* __restrict__ cursor) {
    int gid = blockIdx.x * 256 + threadIdx.x;
    if (gid >= N_NODES) return;
    int o = offsets[gid] + blockSums[blockIdx.x];
    offsets[gid] = o;
    cursor[gid]  = o;
}

// Scatter src indices into dst-sorted order.
__global__ void scatter(const int* __restrict__ src,
                        const int* __restrict__ dst,
                        int* __restrict__ cursor,
                        int* __restrict__ sorted_src) {
    int i = blockIdx.x * blockDim.x + threadIdx.x;
    if (i >= N_EDGES) return;
    int pos = atomicAdd(&cursor[dst[i]], 1);
    sorted_src[pos] = src[i];
}

// One wave per destination node. lane = feature dim.
// Fast path (deg <= 64): edge src + softmax weight cached per-lane, broadcast
// via shfl; inner loop = one coalesced 256B h-row load + FMA per edge.
__global__ void node_aggregate(const int* __restrict__ sorted_src,
                               const int* __restrict__ offsets,
                               const int* __restrict__ deg,
                               const float* __restrict__ a_src,
                               const float* __restrict__ a_dst,
                               const float* __restrict__ h,
                               float* __restrict__ out) {
    int wave = (blockIdx.x * blockDim.x + threadIdx.x) >> 6;
    int lane = threadIdx.x & 63;
    if (wave >= N_NODES) return;
    int node = wave;
    int off  = offsets[node];
    int dg   = deg[node];
    float ad = a_dst[node];
    float acc = 0.0f;

    if (dg <= 64) {
        int   my_s = 0;
        float my_e = NEG_INF;
        if (lane < dg) {
            my_s = sorted_src[off + lane];
            my_e = leaky01(a_src[my_s] + ad);
        }
        float m = my_e;
        #pragma unroll
        for (int x = 1; x < 64; x <<= 1) m = fmaxf(m, __shfl_xor(m, x));
        float ex = (lane < dg) ? expf(my_e - m) : 0.0f;
        float ssum = ex;
        #pragma unroll
        for (int x = 1; x < 64; x <<= 1) ssum += __shfl_xor(ssum, x);
        float my_w = ex / ssum;  // NaN only if dg==0 (loop below then empty)
        for (int k = 0; k < dg; ++k) {
            int   s = __shfl(my_s, k);
            float w = __shfl(my_w, k);
            acc = fmaf(w, h[(size_t)s * DIM + lane], acc);
        }
    } else {
        // generic chunked path (deg > 64): recompute e per chunk
        float m = NEG_INF;
        for (int base = 0; base < dg; base += 64) {
            int k = base + lane;
            float e = NEG_INF;
            if (k < dg) {
                int s = sorted_src[off + k];
                e = leaky01(a_src[s] + ad);
            }
            m = fmaxf(m, e);
        }
        #pragma unroll
        for (int x = 1; x < 64; x <<= 1) m = fmaxf(m, __shfl_xor(m, x));
        float ssum = 0.0f;
        for (int base = 0; base < dg; base += 64) {
            int k = base + lane;
            if (k < dg) {
                int s = sorted_src[off + k];
                ssum += expf(leaky01(a_src[s] + ad) - m);
            }
        }
        #pragma unroll
        for (int x = 1; x < 64; x <<= 1) ssum += __shfl_xor(ssum, x);
        float inv = 1.0f / ssum;
        for (int k = 0; k < dg; ++k) {
            int   s = sorted_src[off + k];                 // broadcast load
            float w = expf(leaky01(a_src[s] + ad) - m) * inv;
            acc = fmaf(w, h[(size_t)s * DIM + lane], acc);
        }
    }
    out[(size_t)node * DIM + lane] = acc;  // zero for deg==0, matches segment_sum
}

extern "C" void kernel_launch(void* const* d_in, const int* in_sizes, int n_in,
                              void* d_out, int out_size, void* d_ws, size_t ws_size,
                              hipStream_t stream) {
    const float* h   = (const float*)d_in[0];
    const int*   src = (const int*)d_in[1];
    const int*   dst = (const int*)d_in[2];
    const float* W   = (const float*)d_in[3];
    const float* b   = (const float*)d_in[4];
    float*       out = (float*)d_out;

    // workspace layout
    float* a_src      = (float*)d_ws;            // N
    float* a_dst      = a_src + N_NODES;         // N
    int*   deg        = (int*)(a_dst + N_NODES); // N
    int*   offsets    = deg + N_NODES;           // N
    int*   cursor     = offsets + N_NODES;       // N
    int*   blockSums  = cursor + N_NODES;        // 512
    int*   sorted_src = blockSums + 512;         // E
    // total: 5*N + 512 + E ints ~= 8.4 MB

    hipMemsetAsync(deg, 0, N_NODES * sizeof(int), stream);

    int node_blocks = (N_NODES + 15) / 16;       // 6250 (16 nodes/block)
    node_pre<<<node_blocks, 256, 0, stream>>>(h, W, b, a_src, a_dst);

    int edge_blocks = (N_EDGES + 255) / 256;     // 6250
    hist<<<edge_blocks, 256, 0, stream>>>(dst, deg);

    int scan_blocks = (N_NODES + 255) / 256;     // 391
    scan1<<<scan_blocks, 256, 0, stream>>>(deg, offsets, blockSums);
    scan2<<<1, 512, 0, stream>>>(blockSums, scan_blocks);
    scan3<<<scan_blocks, 256, 0, stream>>>(offsets, blockSums, cursor);

    scatter<<<edge_blocks, 256, 0, stream>>>(src, dst, cursor, sorted_src);

    int agg_blocks = (N_NODES + 3) / 4;          // 25000 (4 waves/block)
    node_aggregate<<<agg_blocks, 256, 0, stream>>>(sorted_src, offsets, deg,
                                                   a_src, a_dst, h, out);
}